// Round 1
// baseline (758.134 us; speedup 1.0000x reference)
//
#include <hip/hip_runtime.h>
#include <stdint.h>

// ---------------------------------------------------------------------------
// MLP: out = gelu_tanh(x @ w1) @ w2, per-expert (E=8, T=2048, H=1024, F=4096)
// Strategy: bf16 MFMA (16x16x32), m97-style 128x128 tile GEMM with
// global_load_lds width-16 staging. Pre-pass converts x->bf16 and
// transposes+converts w1/w2 into [N][K] bf16 layout so both GEMM operands
// are K-contiguous for ds_read_b128 fragment loads.
// ---------------------------------------------------------------------------

typedef __bf16  bf16x8  __attribute__((ext_vector_type(8)));
typedef float   floatx4 __attribute__((ext_vector_type(4)));

__device__ __forceinline__ uint16_t f2bf(float f) {
    uint32_t u = __float_as_uint(f);
    u += 0x7FFF + ((u >> 16) & 1);       // round-to-nearest-even
    return (uint16_t)(u >> 16);
}

__device__ __forceinline__ float gelu_tanh_f(float x) {
    float u = 0.7978845608028654f * (x + 0.044715f * x * x * x);
    return 0.5f * x * (1.0f + tanhf(u));
}

// async global->LDS, 16 bytes per lane. LDS dest must be wave-uniform base +
// lane*16 (m104/m108 caveat) — callers pass &lds[tid*8] style pointers.
__device__ __forceinline__ void async16(const void* g, void* l) {
    __builtin_amdgcn_global_load_lds(
        (__attribute__((address_space(1))) void*)(g),
        (__attribute__((address_space(3))) void*)(l),
        16, 0, 0);
}

// ---------------------------------------------------------------------------
// fp32 -> bf16 elementwise convert (x), 4 elements/thread
// ---------------------------------------------------------------------------
__global__ void cvt_f32_bf16_x4(const float* __restrict__ in,
                                uint16_t* __restrict__ out, int n4) {
    int i = blockIdx.x * blockDim.x + threadIdx.x;
    if (i >= n4) return;
    float4 v = ((const float4*)in)[i];
    ushort4 o;
    o.x = f2bf(v.x); o.y = f2bf(v.y); o.z = f2bf(v.z); o.w = f2bf(v.w);
    ((ushort4*)out)[i] = o;
}

// ---------------------------------------------------------------------------
// Batched transpose + convert: in [E][R][C] fp32 -> out [E][C][R] bf16
// 32x32 LDS tiles, both global phases coalesced.
// ---------------------------------------------------------------------------
__global__ void transpose_cvt(const float* __restrict__ in,
                              uint16_t* __restrict__ out, int R, int C) {
    __shared__ float tile[32][33];
    const int e = blockIdx.z;
    in  += (size_t)e * R * C;
    out += (size_t)e * C * R;
    const int c0 = blockIdx.x * 32, r0 = blockIdx.y * 32;
    const int tx = threadIdx.x & 31, ty = threadIdx.x >> 5;   // ty: 0..7
#pragma unroll
    for (int i = 0; i < 4; ++i)
        tile[ty + i * 8][tx] = in[(size_t)(r0 + ty + i * 8) * C + c0 + tx];
    __syncthreads();
#pragma unroll
    for (int i = 0; i < 4; ++i)
        out[(size_t)(c0 + ty + i * 8) * R + r0 + tx] = f2bf(tile[tx][ty + i * 8]);
}

// ---------------------------------------------------------------------------
// m97-style GEMM: C[M][N] = A[M][K] @ Bt[N][K]^T, bf16 in, fp32 accum.
// 128x128 tile, BK=32, 256 threads = 2x2 waves, 64x64 per wave,
// mfma_f32_16x16x32_bf16 with 4x4 fragments (16 MFMA / K-iter / wave).
// GELU=true: apply gelu_tanh, store bf16. GELU=false: store fp32.
// Batched over blockIdx.z (expert). M,N,K multiples of 128/128/32.
// ---------------------------------------------------------------------------
template <bool GELU>
__global__ void gemm_bt(const uint16_t* __restrict__ A,
                        const uint16_t* __restrict__ Bt,
                        void* __restrict__ Cv, int M, int N, int K) {
    __shared__ __attribute__((aligned(16))) uint16_t lds_a[128 * 32];
    __shared__ __attribute__((aligned(16))) uint16_t lds_b[128 * 32];

    const int e = blockIdx.z;
    A  += (size_t)e * M * K;
    Bt += (size_t)e * N * K;
    const size_t cEbase = (size_t)e * M * N;

    const int tid = threadIdx.x;
    const int rowBase = blockIdx.y * 128;
    const int colBase = blockIdx.x * 128;

    const int lane = tid & 63;
    const int wave = tid >> 6;
    const int wr = wave >> 1, wc = wave & 1;
    const int quad = lane >> 4, l15 = lane & 15;

    // staging: thread t handles 16B chunk c = it*256 + t; row=c/4, kchunk=c%4
    const uint16_t* gA0 = A  + (size_t)(rowBase + (tid >> 2)) * K + (tid & 3) * 8;
    const uint16_t* gB0 = Bt + (size_t)(colBase + (tid >> 2)) * K + (tid & 3) * 8;
    uint16_t* lA0 = &lds_a[tid * 8];
    uint16_t* lB0 = &lds_b[tid * 8];
    const size_t rstep = (size_t)64 * K;   // +64 rows

    floatx4 acc[4][4] = {};

    const int arow = wr * 64 + l15;   // + mi*16
    const int brow = wc * 64 + l15;   // + ni*16
    const int koff = quad * 8;

    for (int k0 = 0; k0 < K; k0 += 32) {
        async16(gA0 + k0,         lA0);
        async16(gA0 + k0 + rstep, lA0 + 256 * 8);
        async16(gB0 + k0,         lB0);
        async16(gB0 + k0 + rstep, lB0 + 256 * 8);
        __syncthreads();   // compiler emits vmcnt(0) drain before s_barrier

        bf16x8 af[4], bfg[4];
#pragma unroll
        for (int i = 0; i < 4; ++i) {
            af[i]  = *(const bf16x8*)&lds_a[(arow + i * 16) * 32 + koff];
            bfg[i] = *(const bf16x8*)&lds_b[(brow + i * 16) * 32 + koff];
        }
#pragma unroll
        for (int mi = 0; mi < 4; ++mi)
#pragma unroll
            for (int ni = 0; ni < 4; ++ni)
                acc[mi][ni] = __builtin_amdgcn_mfma_f32_16x16x32_bf16(
                    af[mi], bfg[ni], acc[mi][ni], 0, 0, 0);
        __syncthreads();
    }

    // epilogue: D elem (row = quad*4 + r, col = l15) within each 16x16 tile
#pragma unroll
    for (int mi = 0; mi < 4; ++mi) {
#pragma unroll
        for (int r = 0; r < 4; ++r) {
            const int row = rowBase + wr * 64 + mi * 16 + quad * 4 + r;
            const size_t base = cEbase + (size_t)row * N + colBase + wc * 64 + l15;
#pragma unroll
            for (int ni = 0; ni < 4; ++ni) {
                float v = acc[mi][ni][r];
                if constexpr (GELU) {
                    ((uint16_t*)Cv)[base + ni * 16] = f2bf(gelu_tanh_f(v));
                } else {
                    ((float*)Cv)[base + ni * 16] = v;
                }
            }
        }
    }
}

// ---------------------------------------------------------------------------
extern "C" void kernel_launch(void* const* d_in, const int* in_sizes, int n_in,
                              void* d_out, int out_size, void* d_ws, size_t ws_size,
                              hipStream_t stream) {
    const float* x  = (const float*)d_in[0];   // [E,T,H]
    const float* w1 = (const float*)d_in[1];   // [E,H,F]
    const float* w2 = (const float*)d_in[2];   // [E,F,H]
    float* out = (float*)d_out;                // [E,T,H] fp32

    const int E = 8, T = 2048, H = 1024, F = 4096;

    // workspace layout (bf16 = uint16_t):
    //   xb  [E][T][H]  32 MiB
    //   w1t [E][F][H]  64 MiB   (w1 transposed)
    //   w2t [E][H][F]  64 MiB   (w2 transposed)
    //   h   [E][T][F] 128 MiB   (gelu output)
    uint16_t* xb  = (uint16_t*)d_ws;
    uint16_t* w1t = xb  + (size_t)E * T * H;
    uint16_t* w2t = w1t + (size_t)E * F * H;
    uint16_t* h   = w2t + (size_t)E * H * F;

    {   // x -> bf16
        int n4 = (E * T * H) / 4;
        cvt_f32_bf16_x4<<<n4 / 256, 256, 0, stream>>>(x, xb, n4);
    }
    // w1 [E][H][F] -> w1t [E][F][H]
    transpose_cvt<<<dim3(F / 32, H / 32, E), 256, 0, stream>>>(w1, w1t, H, F);
    // w2 [E][F][H] -> w2t [E][H][F]
    transpose_cvt<<<dim3(H / 32, F / 32, E), 256, 0, stream>>>(w2, w2t, F, H);

    // GEMM1 + gelu: h[T,F] = gelu(x[T,H] @ w1[H,F]) ; Bt = w1t [F][H]
    gemm_bt<true><<<dim3(F / 128, T / 128, E), 256, 0, stream>>>(xb, w1t, h, T, F, H);
    // GEMM2: out[T,H] = h[T,F] @ w2[F,H] ; Bt = w2t [H][F]
    gemm_bt<false><<<dim3(H / 128, T / 128, E), 256, 0, stream>>>(h, w2t, out, T, H, F);
}

// Round 2
// 733.811 us; speedup vs baseline: 1.0331x; 1.0331x over previous
//
#include <hip/hip_runtime.h>
#include <stdint.h>

// ---------------------------------------------------------------------------
// MLP: out = gelu_tanh(x @ w1) @ w2, per-expert (E=8, T=2048, H=1024, F=4096)
// bf16 MFMA (16x16x32), m97-style 128x128 tile GEMM with global_load_lds
// width-16 staging. Pre-pass converts x->bf16 and transposes+converts w1/w2
// into [N][K] bf16 so both GEMM operands are K-contiguous for ds_read_b128.
// R2: fast transpose (float4 loads, 16B stores), sigmoid-form GELU.
// ---------------------------------------------------------------------------

typedef __bf16  bf16x8  __attribute__((ext_vector_type(8)));
typedef float   floatx4 __attribute__((ext_vector_type(4)));

__device__ __forceinline__ uint16_t f2bf(float f) {
    uint32_t u = __float_as_uint(f);
    u += 0x7FFF + ((u >> 16) & 1);       // round-to-nearest-even
    return (uint16_t)(u >> 16);
}

__device__ __forceinline__ uint32_t pack2bf(float lo, float hi) {
    return (uint32_t)f2bf(lo) | ((uint32_t)f2bf(hi) << 16);
}

// gelu_tanh(x) == x * sigmoid(2u), u = sqrt(2/pi)*(x + 0.044715 x^3)
__device__ __forceinline__ float gelu_tanh_f(float x) {
    float u2 = 1.5957691216057308f * (x + 0.044715f * x * x * x);
    return x / (1.0f + __expf(-u2));
}

// async global->LDS, 16 bytes per lane. LDS dest must be wave-uniform base +
// lane*16 (m104/m108 caveat) — callers pass &lds[tid*8] style pointers.
__device__ __forceinline__ void async16(const void* g, void* l) {
    __builtin_amdgcn_global_load_lds(
        (__attribute__((address_space(1))) void*)(g),
        (__attribute__((address_space(3))) void*)(l),
        16, 0, 0);
}

// ---------------------------------------------------------------------------
// fp32 -> bf16 elementwise convert (x), 4 elements/thread
// ---------------------------------------------------------------------------
__global__ void cvt_f32_bf16_x4(const float* __restrict__ in,
                                uint16_t* __restrict__ out, int n4) {
    int i = blockIdx.x * blockDim.x + threadIdx.x;
    if (i >= n4) return;
    float4 v = ((const float4*)in)[i];
    ushort4 o;
    o.x = f2bf(v.x); o.y = f2bf(v.y); o.z = f2bf(v.z); o.w = f2bf(v.w);
    ((ushort4*)out)[i] = o;
}

// ---------------------------------------------------------------------------
// Batched transpose + convert: in [E][R][C] fp32 -> out [E][C][R] bf16.
// 64x64 tiles, 256 threads. Loads: float4 (fully coalesced). LDS holds the
// transposed tile as packed bf16 pairs (uint32 = rows 2a,2a+1 of one out-row).
// Stores: 2x global_store_dwordx4 per thread, 128B per out-row per wave.
// R and C multiples of 64.
// ---------------------------------------------------------------------------
__global__ void transpose_cvt(const float* __restrict__ in,
                              uint16_t* __restrict__ out, int R, int C) {
    __shared__ uint32_t lds32[64][33];   // [out-row c][row-pair a], +1 pad
    const int e = blockIdx.z;
    in  += (size_t)e * R * C;
    out += (size_t)e * C * R;
    const int c0 = blockIdx.x * 64, r0 = blockIdx.y * 64;
    const int t = threadIdx.x;

    // load 4 rows x 4 cols per thread
    const int g = t >> 4;              // 0..15 -> rows 4g..4g+3
    const int col4 = (t & 15) * 4;     // 0,4,...,60
    const float* p = in + (size_t)(r0 + 4 * g) * C + c0 + col4;
    float4 v0 = ((const float4*)(p))[0];
    float4 v1 = ((const float4*)(p + C))[0];
    float4 v2 = ((const float4*)(p + 2 * (size_t)C))[0];
    float4 v3 = ((const float4*)(p + 3 * (size_t)C))[0];

    lds32[col4 + 0][2 * g]     = pack2bf(v0.x, v1.x);
    lds32[col4 + 1][2 * g]     = pack2bf(v0.y, v1.y);
    lds32[col4 + 2][2 * g]     = pack2bf(v0.z, v1.z);
    lds32[col4 + 3][2 * g]     = pack2bf(v0.w, v1.w);
    lds32[col4 + 0][2 * g + 1] = pack2bf(v2.x, v3.x);
    lds32[col4 + 1][2 * g + 1] = pack2bf(v2.y, v3.y);
    lds32[col4 + 2][2 * g + 1] = pack2bf(v2.z, v3.z);
    lds32[col4 + 3][2 * g + 1] = pack2bf(v2.w, v3.w);
    __syncthreads();

    // store: thread -> out-row c = t>>2, 32B chunk ch = t&3 (16 bf16)
    const int c = t >> 2, ch = t & 3;
    uint32_t v[8];
#pragma unroll
    for (int k = 0; k < 8; ++k) v[k] = lds32[c][ch * 8 + k];
    uint16_t* op = out + (size_t)(c0 + c) * R + r0 + ch * 16;
    *(uint4*)(op)     = make_uint4(v[0], v[1], v[2], v[3]);
    *(uint4*)(op + 8) = make_uint4(v[4], v[5], v[6], v[7]);
}

// ---------------------------------------------------------------------------
// m97-style GEMM: C[M][N] = A[M][K] @ Bt[N][K]^T, bf16 in, fp32 accum.
// 128x128 tile, BK=32, 256 threads = 2x2 waves, 64x64 per wave,
// mfma_f32_16x16x32_bf16 with 4x4 fragments (16 MFMA / K-iter / wave).
// GELU=true: apply gelu_tanh, store bf16. GELU=false: store fp32.
// Batched over blockIdx.z (expert). M,N multiples of 128, K of 32.
// ---------------------------------------------------------------------------
template <bool GELU>
__global__ void gemm_bt(const uint16_t* __restrict__ A,
                        const uint16_t* __restrict__ Bt,
                        void* __restrict__ Cv, int M, int N, int K) {
    __shared__ __attribute__((aligned(16))) uint16_t lds_a[128 * 32];
    __shared__ __attribute__((aligned(16))) uint16_t lds_b[128 * 32];

    const int e = blockIdx.z;
    A  += (size_t)e * M * K;
    Bt += (size_t)e * N * K;
    const size_t cEbase = (size_t)e * M * N;

    const int tid = threadIdx.x;
    const int rowBase = blockIdx.y * 128;
    const int colBase = blockIdx.x * 128;

    const int lane = tid & 63;
    const int wave = tid >> 6;
    const int wr = wave >> 1, wc = wave & 1;
    const int quad = lane >> 4, l15 = lane & 15;

    // staging: thread t handles 16B chunk: row = t>>2 (+64), kchunk = t&3
    const uint16_t* gA0 = A  + (size_t)(rowBase + (tid >> 2)) * K + (tid & 3) * 8;
    const uint16_t* gB0 = Bt + (size_t)(colBase + (tid >> 2)) * K + (tid & 3) * 8;
    uint16_t* lA0 = &lds_a[tid * 8];
    uint16_t* lB0 = &lds_b[tid * 8];
    const size_t rstep = (size_t)64 * K;   // +64 rows

    floatx4 acc[4][4] = {};

    const int arow = wr * 64 + l15;   // + mi*16
    const int brow = wc * 64 + l15;   // + ni*16
    const int koff = quad * 8;

    for (int k0 = 0; k0 < K; k0 += 32) {
        async16(gA0 + k0,         lA0);
        async16(gA0 + k0 + rstep, lA0 + 256 * 8);
        async16(gB0 + k0,         lB0);
        async16(gB0 + k0 + rstep, lB0 + 256 * 8);
        __syncthreads();   // compiler emits vmcnt(0) drain before s_barrier

        bf16x8 af[4], bfg[4];
#pragma unroll
        for (int i = 0; i < 4; ++i) {
            af[i]  = *(const bf16x8*)&lds_a[(arow + i * 16) * 32 + koff];
            bfg[i] = *(const bf16x8*)&lds_b[(brow + i * 16) * 32 + koff];
        }
#pragma unroll
        for (int mi = 0; mi < 4; ++mi)
#pragma unroll
            for (int ni = 0; ni < 4; ++ni)
                acc[mi][ni] = __builtin_amdgcn_mfma_f32_16x16x32_bf16(
                    af[mi], bfg[ni], acc[mi][ni], 0, 0, 0);
        __syncthreads();
    }

    // epilogue: D elem (row = quad*4 + r, col = l15) within each 16x16 tile
#pragma unroll
    for (int mi = 0; mi < 4; ++mi) {
#pragma unroll
        for (int r = 0; r < 4; ++r) {
            const int row = rowBase + wr * 64 + mi * 16 + quad * 4 + r;
            const size_t base = cEbase + (size_t)row * N + colBase + wc * 64 + l15;
#pragma unroll
            for (int ni = 0; ni < 4; ++ni) {
                float v = acc[mi][ni][r];
                if constexpr (GELU) {
                    ((uint16_t*)Cv)[base + ni * 16] = f2bf(gelu_tanh_f(v));
                } else {
                    ((float*)Cv)[base + ni * 16] = v;
                }
            }
        }
    }
}

// ---------------------------------------------------------------------------
extern "C" void kernel_launch(void* const* d_in, const int* in_sizes, int n_in,
                              void* d_out, int out_size, void* d_ws, size_t ws_size,
                              hipStream_t stream) {
    const float* x  = (const float*)d_in[0];   // [E,T,H]
    const float* w1 = (const float*)d_in[1];   // [E,H,F]
    const float* w2 = (const float*)d_in[2];   // [E,F,H]
    float* out = (float*)d_out;                // [E,T,H] fp32

    const int E = 8, T = 2048, H = 1024, F = 4096;

    // workspace layout (bf16 = uint16_t):
    //   xb  [E][T][H]  32 MiB
    //   w1t [E][F][H]  64 MiB   (w1 transposed)
    //   w2t [E][H][F]  64 MiB   (w2 transposed)
    //   h   [E][T][F] 128 MiB   (gelu output)
    uint16_t* xb  = (uint16_t*)d_ws;
    uint16_t* w1t = xb  + (size_t)E * T * H;
    uint16_t* w2t = w1t + (size_t)E * F * H;
    uint16_t* h   = w2t + (size_t)E * H * F;

    {   // x -> bf16
        int n4 = (E * T * H) / 4;
        cvt_f32_bf16_x4<<<n4 / 256, 256, 0, stream>>>(x, xb, n4);
    }
    // w1 [E][H][F] -> w1t [E][F][H]
    transpose_cvt<<<dim3(F / 64, H / 64, E), 256, 0, stream>>>(w1, w1t, H, F);
    // w2 [E][F][H] -> w2t [E][H][F]
    transpose_cvt<<<dim3(H / 64, F / 64, E), 256, 0, stream>>>(w2, w2t, F, H);

    // GEMM1 + gelu: h[T,F] = gelu(x[T,H] @ w1[H,F]) ; Bt = w1t [F][H]
    gemm_bt<true><<<dim3(F / 128, T / 128, E), 256, 0, stream>>>(xb, w1t, h, T, F, H);
    // GEMM2: out[T,H] = h[T,F] @ w2[F,H] ; Bt = w2t [H][F]
    gemm_bt<false><<<dim3(H / 128, T / 128, E), 256, 0, stream>>>(h, w2t, out, T, H, F);
}

// Round 3
// 679.244 us; speedup vs baseline: 1.1161x; 1.0803x over previous
//
#include <hip/hip_runtime.h>
#include <stdint.h>

// ---------------------------------------------------------------------------
// MLP: out = gelu_tanh(x @ w1) @ w2, per-expert (E=8, T=2048, H=1024, F=4096)
// bf16 MFMA (16x16x32), 128x128 tile GEMM, global_load_lds width-16 staging.
// R3: BK=64 (half the barrier drains per K) + XOR-swizzled LDS layout
// (k-chunk kc of row r stored at physical chunk kc^(r&7)) so b128 fragment
// reads are bank-conflict-free at the 128B row stride. Source-side global
// address permutation keeps staging coalesced (global_load_lds dest is
// pinned to base+lane*16).
// ---------------------------------------------------------------------------

typedef __bf16  bf16x8  __attribute__((ext_vector_type(8)));
typedef float   floatx4 __attribute__((ext_vector_type(4)));

__device__ __forceinline__ uint16_t f2bf(float f) {
    uint32_t u = __float_as_uint(f);
    u += 0x7FFF + ((u >> 16) & 1);       // round-to-nearest-even
    return (uint16_t)(u >> 16);
}

__device__ __forceinline__ uint32_t pack2bf(float lo, float hi) {
    return (uint32_t)f2bf(lo) | ((uint32_t)f2bf(hi) << 16);
}

// gelu_tanh(x) == x * sigmoid(2u), u = sqrt(2/pi)*(x + 0.044715 x^3)
__device__ __forceinline__ float gelu_tanh_f(float x) {
    float u2 = 1.5957691216057308f * (x + 0.044715f * x * x * x);
    return x / (1.0f + __expf(-u2));
}

// async global->LDS, 16 bytes per lane; dest = wave-uniform base + lane*16.
__device__ __forceinline__ void async16(const void* g, void* l) {
    __builtin_amdgcn_global_load_lds(
        (__attribute__((address_space(1))) void*)(g),
        (__attribute__((address_space(3))) void*)(l),
        16, 0, 0);
}

// ---------------------------------------------------------------------------
// fp32 -> bf16 elementwise convert (x), 4 elements/thread
// ---------------------------------------------------------------------------
__global__ void cvt_f32_bf16_x4(const float* __restrict__ in,
                                uint16_t* __restrict__ out, int n4) {
    int i = blockIdx.x * blockDim.x + threadIdx.x;
    if (i >= n4) return;
    float4 v = ((const float4*)in)[i];
    ushort4 o;
    o.x = f2bf(v.x); o.y = f2bf(v.y); o.z = f2bf(v.z); o.w = f2bf(v.w);
    ((ushort4*)out)[i] = o;
}

// ---------------------------------------------------------------------------
// Batched transpose + convert: in [E][R][C] fp32 -> out [E][C][R] bf16.
// 64x64 tiles, 256 threads; float4 loads, 16B stores. R,C multiples of 64.
// ---------------------------------------------------------------------------
__global__ void transpose_cvt(const float* __restrict__ in,
                              uint16_t* __restrict__ out, int R, int C) {
    __shared__ uint32_t lds32[64][33];   // [out-row c][row-pair a], +1 pad
    const int e = blockIdx.z;
    in  += (size_t)e * R * C;
    out += (size_t)e * C * R;
    const int c0 = blockIdx.x * 64, r0 = blockIdx.y * 64;
    const int t = threadIdx.x;

    const int g = t >> 4;              // 0..15 -> rows 4g..4g+3
    const int col4 = (t & 15) * 4;     // 0,4,...,60
    const float* p = in + (size_t)(r0 + 4 * g) * C + c0 + col4;
    float4 v0 = ((const float4*)(p))[0];
    float4 v1 = ((const float4*)(p + C))[0];
    float4 v2 = ((const float4*)(p + 2 * (size_t)C))[0];
    float4 v3 = ((const float4*)(p + 3 * (size_t)C))[0];

    lds32[col4 + 0][2 * g]     = pack2bf(v0.x, v1.x);
    lds32[col4 + 1][2 * g]     = pack2bf(v0.y, v1.y);
    lds32[col4 + 2][2 * g]     = pack2bf(v0.z, v1.z);
    lds32[col4 + 3][2 * g]     = pack2bf(v0.w, v1.w);
    lds32[col4 + 0][2 * g + 1] = pack2bf(v2.x, v3.x);
    lds32[col4 + 1][2 * g + 1] = pack2bf(v2.y, v3.y);
    lds32[col4 + 2][2 * g + 1] = pack2bf(v2.z, v3.z);
    lds32[col4 + 3][2 * g + 1] = pack2bf(v2.w, v3.w);
    __syncthreads();

    const int c = t >> 2, ch = t & 3;
    uint32_t v[8];
#pragma unroll
    for (int k = 0; k < 8; ++k) v[k] = lds32[c][ch * 8 + k];
    uint16_t* op = out + (size_t)(c0 + c) * R + r0 + ch * 16;
    *(uint4*)(op)     = make_uint4(v[0], v[1], v[2], v[3]);
    *(uint4*)(op + 8) = make_uint4(v[4], v[5], v[6], v[7]);
}

// ---------------------------------------------------------------------------
// GEMM: C[M][N] = A[M][K] @ Bt[N][K]^T, bf16 in, fp32 accum.
// 128x128 tile, BK=64, 256 threads = 2x2 waves, 64x64 per wave,
// mfma_f32_16x16x32_bf16, 4x4 fragments, 32 MFMA / K-iter / wave.
// LDS: [row][64] elems, physical 8-elem chunk pc = kc ^ (row&7) (XOR swizzle;
// bank-conflict-free b128 reads). GELU=true: gelu+bf16 store; else fp32.
// Batched over blockIdx.z. M,N mult of 128, K mult of 64.
// ---------------------------------------------------------------------------
template <bool GELU>
__global__ void gemm_bt(const uint16_t* __restrict__ A,
                        const uint16_t* __restrict__ Bt,
                        void* __restrict__ Cv, int M, int N, int K) {
    __shared__ __attribute__((aligned(16))) uint16_t lds_a[128 * 64];
    __shared__ __attribute__((aligned(16))) uint16_t lds_b[128 * 64];

    const int e = blockIdx.z;
    A  += (size_t)e * M * K;
    Bt += (size_t)e * N * K;
    const size_t cEbase = (size_t)e * M * N;

    const int tid = threadIdx.x;
    const int rowBase = blockIdx.y * 128;
    const int colBase = blockIdx.x * 128;

    const int lane = tid & 63;
    const int wave = tid >> 6;
    const int wr = wave >> 1, wc = wave & 1;
    const int quad = lane >> 4, l15 = lane & 15;

    // staging: thread t -> LDS slot (row = i*32 + (t>>3), pc = t&7).
    // Slot pc holds logical k-chunk kc = pc ^ (row&7); row&7 == (t>>3)&7,
    // loop-invariant, folded into the global base address.
    const int srow  = tid >> 3;
    const int sxor  = ((tid & 7) ^ (srow & 7)) * 8;   // logical k offset (elems)
    const uint16_t* gA0 = A  + (size_t)(rowBase + srow) * K + sxor;
    const uint16_t* gB0 = Bt + (size_t)(colBase + srow) * K + sxor;
    uint16_t* lA0 = &lds_a[tid * 8];
    uint16_t* lB0 = &lds_b[tid * 8];
    const size_t rstep = (size_t)32 * K;   // +32 rows per staging iter

    floatx4 acc[4][4] = {};

    const int arow = wr * 64 + l15;   // + mi*16 (mi*16 preserves row&7)
    const int brow = wc * 64 + l15;   // + ni*16
    const int axor = l15 & 7;         // row&7 for fragment rows

    for (int k0 = 0; k0 < K; k0 += 64) {
#pragma unroll
        for (int i = 0; i < 4; ++i) {
            async16(gA0 + k0 + i * rstep, lA0 + i * 2048);
            async16(gB0 + k0 + i * rstep, lB0 + i * 2048);
        }
        __syncthreads();

#pragma unroll
        for (int s = 0; s < 2; ++s) {           // two 32-deep k sub-steps
            const int pcA = ((s * 4 + quad) ^ axor) * 8;
            bf16x8 af[4], bfg[4];
#pragma unroll
            for (int i = 0; i < 4; ++i) {
                af[i]  = *(const bf16x8*)&lds_a[(arow + i * 16) * 64 + pcA];
                bfg[i] = *(const bf16x8*)&lds_b[(brow + i * 16) * 64 + pcA];
            }
#pragma unroll
            for (int mi = 0; mi < 4; ++mi)
#pragma unroll
                for (int ni = 0; ni < 4; ++ni)
                    acc[mi][ni] = __builtin_amdgcn_mfma_f32_16x16x32_bf16(
                        af[mi], bfg[ni], acc[mi][ni], 0, 0, 0);
        }
        __syncthreads();
    }

    // epilogue: D elem (row = quad*4 + r, col = l15) within each 16x16 tile
#pragma unroll
    for (int mi = 0; mi < 4; ++mi) {
#pragma unroll
        for (int r = 0; r < 4; ++r) {
            const int row = rowBase + wr * 64 + mi * 16 + quad * 4 + r;
            const size_t base = cEbase + (size_t)row * N + colBase + wc * 64 + l15;
#pragma unroll
            for (int ni = 0; ni < 4; ++ni) {
                float v = acc[mi][ni][r];
                if constexpr (GELU) {
                    ((uint16_t*)Cv)[base + ni * 16] = f2bf(gelu_tanh_f(v));
                } else {
                    ((float*)Cv)[base + ni * 16] = v;
                }
            }
        }
    }
}

// ---------------------------------------------------------------------------
extern "C" void kernel_launch(void* const* d_in, const int* in_sizes, int n_in,
                              void* d_out, int out_size, void* d_ws, size_t ws_size,
                              hipStream_t stream) {
    const float* x  = (const float*)d_in[0];   // [E,T,H]
    const float* w1 = (const float*)d_in[1];   // [E,H,F]
    const float* w2 = (const float*)d_in[2];   // [E,F,H]
    float* out = (float*)d_out;                // [E,T,H] fp32

    const int E = 8, T = 2048, H = 1024, F = 4096;

    uint16_t* xb  = (uint16_t*)d_ws;                    //  32 MiB
    uint16_t* w1t = xb  + (size_t)E * T * H;            //  64 MiB
    uint16_t* w2t = w1t + (size_t)E * F * H;            //  64 MiB
    uint16_t* h   = w2t + (size_t)E * H * F;            // 128 MiB

    {   // x -> bf16
        int n4 = (E * T * H) / 4;
        cvt_f32_bf16_x4<<<n4 / 256, 256, 0, stream>>>(x, xb, n4);
    }
    // w1 [E][H][F] -> w1t [E][F][H]
    transpose_cvt<<<dim3(F / 64, H / 64, E), 256, 0, stream>>>(w1, w1t, H, F);
    // w2 [E][F][H] -> w2t [E][H][F]
    transpose_cvt<<<dim3(H / 64, F / 64, E), 256, 0, stream>>>(w2, w2t, F, H);

    // GEMM1 + gelu: h[T,F] = gelu(x[T,H] @ w1[H,F]) ; Bt = w1t [F][H]
    gemm_bt<true><<<dim3(F / 128, T / 128, E), 256, 0, stream>>>(xb, w1t, h, T, F, H);
    // GEMM2: out[T,H] = h[T,F] @ w2[F,H] ; Bt = w2t [H][F]
    gemm_bt<false><<<dim3(H / 128, T / 128, E), 256, 0, stream>>>(h, w2t, out, T, H, F);
}